// Round 6
// baseline (282.687 us; speedup 1.0000x reference)
//
#include <hip/hip_runtime.h>

// VectorQuantizer: N=262144 rows, D=64 dims, K=512 codewords, fp32.
// out layout (floats): [0,N) idx ; [N, N+N*D) quantized_st ; [N+N*D] vq_loss
//
// CORRECTNESS MODEL (verified R2-R5, absmax 0): reference fp32 bit pattern is
//   d2 = fl(fl(x2 - fl(2*m)) + w2), x2/w2 numpy pairwise-8 order, m = sequential
//   FMA chain d ascending (BLAS), argmin strict < (first-min tie-break).
// Two-phase: MFMA approx scores (bf16 hi/mid splits of -2w, 3 terms) +
// exact-chain recheck of rows with top-2 gap < margin. The flag/recheck logic
// is correct for ANY approx whose error <= bound.
//
// R10 (resubmit — R5 bench was an infra failure, no measurement):
// (a) epilogue memory-path rewrite — row-per-thread float4 at 256B lane
// stride was 4x transaction-inflated on BOTH x-read and q-write; now staged
// through padded LDS tiles with coalesced global access. Per-thread fmaf
// chain / wave composition / red[] / atomicAdd structure UNCHANGED => loss
// and q bit-identical. (b) T5 s_setprio around MFMA clusters in vq_gemm
// (independent-block regime, where setprio measured positive).
#define NROWS 262144
#define DDIM  64
#define KCB   512

// key = (fp32 bits of s''=w2+3-2*dot) << 9 | cw ; s'' in [2.8,3.2] => one
// exponent octave => bits monotone. 1 key unit = ulp(3)/512 ; MARGKEY = 3<<17
// => 768 ulps = 1.83e-4 >= 2x worst-case |approx - ref| bound (~9.1e-5).
#define MARGKEY (3u << 17)

// ws layout (bytes)
#define WS_CNT   0
#define WS_W2P3  1024
#define WS_WHI   4096
#define WS_WMID  69632
#define WS_LIST  135168

typedef __attribute__((ext_vector_type(8))) short short8;
typedef __attribute__((ext_vector_type(4))) float floatx4;
typedef __attribute__((ext_vector_type(16))) float floatx16;
typedef __attribute__((ext_vector_type(2))) unsigned int uintx2;

#if defined(__has_builtin)
#if __has_builtin(__builtin_amdgcn_permlane32_swap)
#define VQ_PLSWAP 1
#endif
#endif

__device__ __forceinline__ unsigned umin2(unsigned a, unsigned b) { return a < b ? a : b; }
__device__ __forceinline__ unsigned umax2(unsigned a, unsigned b) { return a > b ? a : b; }

// numpy FLOAT_pairwise_sum order for n=64 over terms fl(a[i]*a[i])  [R2-verified]
__device__ __forceinline__ float np_sumsq64(const float* a) {
    float r[8];
#pragma unroll
    for (int j = 0; j < 8; ++j) r[j] = __fmul_rn(a[j], a[j]);
#pragma unroll
    for (int i = 8; i < 64; i += 8) {
#pragma unroll
        for (int j = 0; j < 8; ++j)
            r[j] = __fadd_rn(r[j], __fmul_rn(a[i + j], a[i + j]));
    }
    return __fadd_rn(__fadd_rn(__fadd_rn(r[0], r[1]), __fadd_rn(r[2], r[3])),
                     __fadd_rn(__fadd_rn(r[4], r[5]), __fadd_rn(r[6], r[7])));
}

// pack two fp32 into bf16-truncate hi dword + residual-bf16 mid dword
__device__ __forceinline__ void split2(float e0, float e1, unsigned& hid, unsigned& mid) {
    unsigned u0 = __float_as_uint(e0), u1 = __float_as_uint(e1);
    float r0 = __fsub_rn(e0, __uint_as_float(u0 & 0xFFFF0000u));  // exact
    float r1 = __fsub_rn(e1, __uint_as_float(u1 & 0xFFFF0000u));  // exact
    hid = (u0 >> 16) | (u1 & 0xFFFF0000u);
    mid = (__float_as_uint(r0) >> 16) | (__float_as_uint(r1) & 0xFFFF0000u);
}

__device__ __forceinline__ void split4(float4 v, uint2& h, uint2& m) {
    unsigned h0, m0, h1, m1;
    split2(v.x, v.y, h0, m0);
    split2(v.z, v.w, h1, m1);
    h = make_uint2(h0, h1);
    m = make_uint2(m0, m1);
}

// xor-32 merge of (min1,min2) pairs across lane halves.
__device__ __forceinline__ void merge32(unsigned& m1, unsigned& m2) {
#ifdef VQ_PLSWAP
    uintx2 s1 = __builtin_amdgcn_permlane32_swap(m1, m1, false, false);
    uintx2 s2 = __builtin_amdgcn_permlane32_swap(m2, m2, false, false);
    m2 = umin2(umin2(s2[0], s2[1]), umax2(s1[0], s1[1]));
    m1 = umin2(s1[0], s1[1]);
#else
    unsigned o1 = __shfl_xor((int)m1, 32);
    unsigned o2 = __shfl_xor((int)m2, 32);
    m2 = umin2(umin2(m2, o2), umax2(m1, o1));
    m1 = umin2(m1, o1);
#endif
}

// top-2 (min1,min2) of 16 keys, balanced tree
__device__ __forceinline__ void top2_16(const unsigned* k, unsigned& m1, unsigned& m2) {
    unsigned lo[8], hi[8];
#pragma unroll
    for (int i = 0; i < 8; ++i) {
        lo[i] = umin2(k[2 * i], k[2 * i + 1]);
        hi[i] = umax2(k[2 * i], k[2 * i + 1]);
    }
#pragma unroll
    for (int s = 4; s >= 1; s >>= 1) {
#pragma unroll
        for (int i = 0; i < s; ++i) {
            unsigned l = umin2(lo[i], lo[i + s]);
            unsigned h = umin2(umax2(lo[i], lo[i + s]), umin2(hi[i], hi[i + s]));
            lo[i] = l; hi[i] = h;
        }
    }
    m1 = lo[0]; m2 = hi[0];
}

// ---- prep: w2p3 = fl(w2)+3, bf16 truncated splits of v = -2*w; zeroes
// cnt/loss (replaces memsets). Bit-identical tables to R5. ----
__global__ void vq_prep(const float* __restrict__ w, float* __restrict__ w2p3,
                        unsigned short* __restrict__ whi,
                        unsigned short* __restrict__ wmid,
                        unsigned* __restrict__ cnt, float* __restrict__ loss) {
    const int k = blockIdx.x * blockDim.x + threadIdx.x;  // 0..511
    if (k == 0) { *cnt = 0u; *loss = 0.0f; }
    float ws[64];
    const float4* wp = (const float4*)(w + (size_t)k * DDIM);
#pragma unroll
    for (int j = 0; j < 16; ++j) {
        float4 v = wp[j];
        ws[4 * j + 0] = v.x; ws[4 * j + 1] = v.y;
        ws[4 * j + 2] = v.z; ws[4 * j + 3] = v.w;
    }
    w2p3[k] = __fadd_rn(np_sumsq64(ws), 3.0f);
#pragma unroll
    for (int j = 0; j < 8; ++j) {
        union { unsigned d[4]; short8 s; } H, M;
#pragma unroll
        for (int t = 0; t < 4; ++t) {
            float v0 = __fmul_rn(-2.0f, ws[8 * j + 2 * t]);      // exact (pow2)
            float v1 = __fmul_rn(-2.0f, ws[8 * j + 2 * t + 1]);  // exact (pow2)
            split2(v0, v1, H.d[t], M.d[t]);
        }
        *(short8*)(whi  + (size_t)k * 64 + 8 * j) = H.s;
        *(short8*)(wmid + (size_t)k * 64 + 8 * j) = M.s;
    }
}

// ---- phase-1: 2048 blocks of 256 thr = 4 waves. Block = (row-tile of 256) x
// (codebook half of 256 cw). Wave owns 64 cw = 2x 32x32x16 cw-tiles; 32
// rows/iter double-buffered LDS staging. Per lane: one x-row (col=lane&31),
// 32 cw values -> lane-local top-2 -> single merge32. ----
__launch_bounds__(256, 4)
__global__ void vq_gemm(const float* __restrict__ x,
                        const unsigned short* __restrict__ whi,
                        const unsigned short* __restrict__ wmid,
                        const float* __restrict__ w2p3g,
                        uint2* __restrict__ mmg) {
    const int tid = threadIdx.x;
    const int wave = tid >> 6, lane = tid & 63;
    const int row32 = lane & 31;   // A: cw-in-tile; B: x-row; C: x-row (col)
    const int khalf = lane >> 5;   // A/B: k-subwindow; C: cw-subset offset/4
    const int half = blockIdx.x & 1;
    const int r0 = (blockIdx.x >> 1) * 256;

    __shared__ float w2p3s[256];                         // 1 KB (this half)
    __shared__ __align__(16) unsigned sbh[2][32 * 36];   // B hi tiles (9 KB)
    __shared__ __align__(16) unsigned sbm[2][32 * 36];   // B mid tiles (9 KB)
    __shared__ uint2 mm[4][8][32];                       // per-wave min1/min2 (8 KB)

    w2p3s[tid] = w2p3g[half * 256 + tid];

    // A-frags: tile tt (32 cw), k-step t (16 dims). Lane holds
    // cw = half*256 + wave*64 + tt*32 + row32, dims t*16 + khalf*8 + j.
    short8 ah[2][4], am[2][4];
#pragma unroll
    for (int tt = 0; tt < 2; ++tt) {
        const size_t cw = (size_t)(half * 256 + wave * 64 + tt * 32 + row32);
#pragma unroll
        for (int t = 0; t < 4; ++t) {
            const size_t off = cw * 64 + t * 16 + khalf * 8;
            ah[tt][t] = *(const short8*)(whi + off);
            am[tt][t] = *(const short8*)(wmid + off);
        }
    }

    // staging: 256 threads stage 32 rows x 16 float4: thread owns rows srow,
    // srow+16 at float4-col sc4.
    const int srow = tid >> 4, sc4 = tid & 15;
    {
        float4 v0 = *(const float4*)(x + (size_t)(r0 + srow) * DDIM + 4 * sc4);
        float4 v1 = *(const float4*)(x + (size_t)(r0 + srow + 16) * DDIM + 4 * sc4);
        uint2 h, m;
        split4(v0, h, m);
        *(uint2*)&sbh[0][srow * 36 + 2 * sc4] = h;
        *(uint2*)&sbm[0][srow * 36 + 2 * sc4] = m;
        split4(v1, h, m);
        *(uint2*)&sbh[0][(srow + 16) * 36 + 2 * sc4] = h;
        *(uint2*)&sbm[0][(srow + 16) * 36 + 2 * sc4] = m;
    }
    __syncthreads();

    // key cw base for this lane's C-subset: + tt*32 + (reg&3)+8*(reg>>2)
    const unsigned cwk = (unsigned)(half * 256 + wave * 64 + 4 * khalf);

    for (int it = 0; it < 8; ++it) {
        const int p = it & 1;
        float4 pre0, pre1;
        if (it < 7) {
            pre0 = *(const float4*)(x + (size_t)(r0 + (it + 1) * 32 + srow) * DDIM + 4 * sc4);
            pre1 = *(const float4*)(x + (size_t)(r0 + (it + 1) * 32 + srow + 16) * DDIM + 4 * sc4);
        }

        // B-frags: row = row32, k-step t: dwords t*8 + khalf*4 .. +3
        short8 bh[4], bm[4];
#pragma unroll
        for (int t = 0; t < 4; ++t) {
            bh[t] = *(const short8*)&sbh[p][row32 * 36 + t * 8 + khalf * 4];
            bm[t] = *(const short8*)&sbm[p][row32 * 36 + t * 8 + khalf * 4];
        }

        unsigned r1t[2], r2t[2];
#pragma unroll
        for (int tt = 0; tt < 2; ++tt) {
            // acc init: reg 4g+i -> m = i + 8g + 4*khalf (contiguous quads)
            floatx16 acc;
            const int wb = wave * 64 + tt * 32 + 4 * khalf;
#pragma unroll
            for (int g = 0; g < 4; ++g) {
                floatx4 v = *(const floatx4*)&w2p3s[wb + 8 * g];
                acc[4 * g + 0] = v[0]; acc[4 * g + 1] = v[1];
                acc[4 * g + 2] = v[2]; acc[4 * g + 3] = v[3];
            }
            __builtin_amdgcn_s_setprio(1);   // T5: favor MFMA-issuing wave
#pragma unroll
            for (int t = 0; t < 4; ++t) {
                acc = __builtin_amdgcn_mfma_f32_32x32x16_bf16(ah[tt][t], bh[t], acc, 0, 0, 0);
                acc = __builtin_amdgcn_mfma_f32_32x32x16_bf16(ah[tt][t], bm[t], acc, 0, 0, 0);
                acc = __builtin_amdgcn_mfma_f32_32x32x16_bf16(am[tt][t], bh[t], acc, 0, 0, 0);
            }
            __builtin_amdgcn_s_setprio(0);
            // keys for this tile's 16 lane-local cw
            unsigned keys[16];
#pragma unroll
            for (int r = 0; r < 16; ++r) {
                const unsigned moff = (unsigned)((r & 3) + 8 * (r >> 2) + tt * 32);
                keys[r] = (__float_as_uint(acc[r]) << 9) + cwk + moff;
            }
            top2_16(keys, r1t[tt], r2t[tt]);
        }
        unsigned m1 = umin2(r1t[0], r1t[1]);
        unsigned m2 = umin2(umax2(r1t[0], r1t[1]), umin2(r2t[0], r2t[1]));
        merge32(m1, m2);   // combine complementary cw subsets (same x-row)
        if (lane < 32) mm[wave][it][row32] = make_uint2(m1, m2);

        if (it < 7) {
            uint2 h, m;
            split4(pre0, h, m);
            *(uint2*)&sbh[p ^ 1][srow * 36 + 2 * sc4] = h;
            *(uint2*)&sbm[p ^ 1][srow * 36 + 2 * sc4] = m;
            split4(pre1, h, m);
            *(uint2*)&sbh[p ^ 1][(srow + 16) * 36 + 2 * sc4] = h;
            *(uint2*)&sbm[p ^ 1][(srow + 16) * 36 + 2 * sc4] = m;
        }
        __syncthreads();
    }

    // deferred cross-wave merge: thread tid owns row r0+tid (it=tid>>5, rl=tid&31)
    unsigned a1 = 0xFFFFFFFFu, a2 = 0xFFFFFFFFu;
#pragma unroll
    for (int wv = 0; wv < 4; ++wv) {
        uint2 v = mm[wv][tid >> 5][tid & 31];
        a2 = umin2(umin2(a2, v.y), umax2(a1, v.x));
        a1 = umin2(a1, v.x);
    }
    mmg[(size_t)half * NROWS + (r0 + tid)] = make_uint2(a1, a2);
}

// ---- merge halves: combine the two 256-cw top-2 results per row, write idx,
// flag rows with top-2 gap < margin into the recheck list. ----
__launch_bounds__(256)
__global__ void vq_merge(const uint2* __restrict__ mmg,
                         float* __restrict__ out_idx,
                         unsigned* __restrict__ cnt,
                         unsigned* __restrict__ list, int listcap) {
    const int row = blockIdx.x * 256 + threadIdx.x;
    const int lane = threadIdx.x & 63;
    uint2 v0 = mmg[row];
    uint2 v1 = mmg[(size_t)NROWS + row];
    unsigned a1 = umin2(v0.x, v1.x);
    unsigned a2 = umin2(umax2(v0.x, v1.x), umin2(v0.y, v1.y));
    out_idx[row] = (float)(a1 & 511u);
    bool flag = (a2 - a1 < MARGKEY);
    unsigned long long mask = __ballot(flag);
    int nw = __popcll(mask);
    unsigned base = 0;
    if (lane == 0 && nw) base = atomicAdd(cnt, (unsigned)nw);
    base = (unsigned)__shfl((int)base, 0);
    if (flag) {
        unsigned pos = base + (unsigned)__popcll(mask & ((1ull << lane) - 1ull));
        if ((int)pos < listcap) list[pos] = (unsigned)row;
    }
}

// ---- recheck: R4-verified structure (thread owns codeword, exact chains,
// LDS d2 tile + exact argmin), rows indirect via flag list ----
__launch_bounds__(512, 4)
__global__ void vq_recheck(const float* __restrict__ x,
                           const float* __restrict__ w,
                           const unsigned* __restrict__ cnt,
                           const unsigned* __restrict__ list, int listcap,
                           float* __restrict__ out_idx) {
    const int tid = threadIdx.x;
    unsigned total = *cnt;
    if (total > (unsigned)listcap) total = (unsigned)listcap;
    const unsigned nb = (total + 15) >> 4;
    if (blockIdx.x >= nb) return;   // early out BEFORE the w-load (uniform)

    // this thread's codeword + its exact w2 (numpy order)
    float wl[64];
    {
        const float4* wp = (const float4*)(w + (size_t)tid * DDIM);
#pragma unroll
        for (int j = 0; j < 16; ++j) {
            float4 v = wp[j];
            wl[4 * j + 0] = v.x; wl[4 * j + 1] = v.y;
            wl[4 * j + 2] = v.z; wl[4 * j + 3] = v.w;
        }
    }
    const float w2l = np_sumsq64(wl);

    __shared__ float d2tile[16][KCB];   // 32 KB
    __shared__ int rowbuf[16];
    __shared__ float x2buf[16];

    for (unsigned batch = blockIdx.x; batch < nb; batch += gridDim.x) {
        if (tid < 16) {
            unsigned li = batch * 16 + (unsigned)tid;
            rowbuf[tid] = (li < total) ? (int)list[li] : -1;
        }
        __syncthreads();

        // x2 per row: 8 threads/row, numpy pairwise-8 order + exact shfl tree
        if (tid < 128) {
            const int rl = tid >> 3, j = tid & 7;
            int row = rowbuf[rl]; if (row < 0) row = 0;
            const float* xr = x + (size_t)row * DDIM;
            float a0 = xr[j];
            float r = __fmul_rn(a0, a0);
#pragma unroll
            for (int i = 1; i < 8; ++i) {
                float ai = xr[8 * i + j];
                r = __fadd_rn(r, __fmul_rn(ai, ai));
            }
            float s1 = __fadd_rn(r,  __shfl_xor(r, 1));
            float s2 = __fadd_rn(s1, __shfl_xor(s1, 2));
            float s4 = __fadd_rn(s2, __shfl_xor(s2, 4));
            if (j == 0) x2buf[rl] = s4;
        }
        __syncthreads();

        // exact chains: 4 rows in flight, block-uniform broadcast x loads
        for (int g = 0; g < 16; g += 4) {
            int ra = rowbuf[g + 0]; if (ra < 0) ra = 0;
            int rb = rowbuf[g + 1]; if (rb < 0) rb = 0;
            int rc = rowbuf[g + 2]; if (rc < 0) rc = 0;
            int rd = rowbuf[g + 3]; if (rd < 0) rd = 0;
            const float* xr0 = x + (size_t)ra * DDIM;
            const float* xr1 = x + (size_t)rb * DDIM;
            const float* xr2 = x + (size_t)rc * DDIM;
            const float* xr3 = x + (size_t)rd * DDIM;
            float m0 = 0.f, m1 = 0.f, m2 = 0.f, m3 = 0.f;
#pragma unroll
            for (int jb = 0; jb < 16; ++jb) {
                float4 a0 = *(const float4*)(xr0 + 4 * jb);
                float4 a1 = *(const float4*)(xr1 + 4 * jb);
                float4 a2 = *(const float4*)(xr2 + 4 * jb);
                float4 a3 = *(const float4*)(xr3 + 4 * jb);
                m0 = __fmaf_rn(a0.x, wl[4 * jb + 0], m0);
                m0 = __fmaf_rn(a0.y, wl[4 * jb + 1], m0);
                m0 = __fmaf_rn(a0.z, wl[4 * jb + 2], m0);
                m0 = __fmaf_rn(a0.w, wl[4 * jb + 3], m0);
                m1 = __fmaf_rn(a1.x, wl[4 * jb + 0], m1);
                m1 = __fmaf_rn(a1.y, wl[4 * jb + 1], m1);
                m1 = __fmaf_rn(a1.z, wl[4 * jb + 2], m1);
                m1 = __fmaf_rn(a1.w, wl[4 * jb + 3], m1);
                m2 = __fmaf_rn(a2.x, wl[4 * jb + 0], m2);
                m2 = __fmaf_rn(a2.y, wl[4 * jb + 1], m2);
                m2 = __fmaf_rn(a2.z, wl[4 * jb + 2], m2);
                m2 = __fmaf_rn(a2.w, wl[4 * jb + 3], m2);
                m3 = __fmaf_rn(a3.x, wl[4 * jb + 0], m3);
                m3 = __fmaf_rn(a3.y, wl[4 * jb + 1], m3);
                m3 = __fmaf_rn(a3.z, wl[4 * jb + 2], m3);
                m3 = __fmaf_rn(a3.w, wl[4 * jb + 3], m3);
            }
            float X0 = x2buf[g + 0], X1 = x2buf[g + 1];
            float X2 = x2buf[g + 2], X3 = x2buf[g + 3];
            d2tile[g + 0][tid] = __fadd_rn(__fsub_rn(X0, __fmul_rn(2.0f, m0)), w2l);
            d2tile[g + 1][tid] = __fadd_rn(__fsub_rn(X1, __fmul_rn(2.0f, m1)), w2l);
            d2tile[g + 2][tid] = __fadd_rn(__fsub_rn(X2, __fmul_rn(2.0f, m2)), w2l);
            d2tile[g + 3][tid] = __fadd_rn(__fsub_rn(X3, __fmul_rn(2.0f, m3)), w2l);
        }
        __syncthreads();

        // exact argmin per row: 32 threads/row, strict < first-min [R4-verified]
        {
            const int rl  = tid >> 5;
            const int sub = tid & 31;
            float bv = d2tile[rl][sub];
            int   bi = sub;
#pragma unroll
            for (int i = 1; i < 16; ++i) {
                int cc = sub + 32 * i;
                float v = d2tile[rl][cc];
                if (v < bv) { bv = v; bi = cc; }
            }
#pragma unroll
            for (int s = 1; s < 32; s <<= 1) {
                float ov = __shfl_xor(bv, s);
                int   oi = __shfl_xor(bi, s);
                if (ov < bv || (ov == bv && oi < bi)) { bv = ov; bi = oi; }
            }
            if (sub == 0 && rowbuf[rl] >= 0) out_idx[rowbuf[rl]] = (float)bi;
        }
        __syncthreads();
    }
}

// ---- epilogue: gather codeword, quantized_st = fl(x + fl(q-x)), loss.
// R10: memory path via padded LDS tiles (coalesced global load/store, 4x
// fewer transactions). Per-thread row ownership (tid->row), fmaf chain order,
// wave shfl tree, red[4] combine, and atomicAdd structure are UNCHANGED =>
// loss and q bit-identical to the R4-verified epilogue. ----
__launch_bounds__(256)
__global__ void vq_epilogue(const float* __restrict__ x,
                            const float* __restrict__ w,
                            const float* __restrict__ out_idx_f,
                            float* __restrict__ out_q,
                            float* __restrict__ out_loss) {
    const int tid = threadIdx.x;
    const int r0  = blockIdx.x * 256;
    const int bidx = (int)out_idx_f[r0 + tid];   // coalesced idx load
    const float4* wq = (const float4*)(w + (size_t)bidx * DDIM);

    __shared__ float tile[128][65];   // 33.3 KB, +1 pad => conflict-minimal
    __shared__ float red[4];

    float ls = 0.0f;
#pragma unroll
    for (int ph = 0; ph < 2; ++ph) {
        const int rb = r0 + ph * 128;
        __syncthreads();   // prior store-phase reads done before overwrite
        // coalesced load: 128 rows x 16 float4 = 2048 float4; 8 per thread
#pragma unroll
        for (int i = 0; i < 8; ++i) {
            const int li = tid + 256 * i;            // linear float4 index
            const int row = li >> 4, c4 = li & 15;
            float4 v = *(const float4*)(x + (size_t)(rb + row) * DDIM + 4 * c4);
            *(float4*)&tile[row][4 * c4] = v;
        }
        __syncthreads();
        // compute: threads ph*128..ph*128+127 own their row (tid->row kept)
        if ((tid >> 7) == ph) {
            const int lr = tid & 127;
#pragma unroll
            for (int j = 0; j < 16; ++j) {
                float4 xv = *(const float4*)&tile[lr][4 * j];
                float4 wv = wq[j];
                float e0 = __fsub_rn(wv.x, xv.x), e1 = __fsub_rn(wv.y, xv.y);
                float e2 = __fsub_rn(wv.z, xv.z), e3 = __fsub_rn(wv.w, xv.w);
                ls = fmaf(e0, e0, ls); ls = fmaf(e1, e1, ls);
                ls = fmaf(e2, e2, ls); ls = fmaf(e3, e3, ls);
                float4 q;
                q.x = __fadd_rn(xv.x, e0); q.y = __fadd_rn(xv.y, e1);
                q.z = __fadd_rn(xv.z, e2); q.w = __fadd_rn(xv.w, e3);
                *(float4*)&tile[lr][4 * j] = q;   // own-row slot, in place
            }
        }
        __syncthreads();
        // coalesced store of q from LDS
#pragma unroll
        for (int i = 0; i < 8; ++i) {
            const int li = tid + 256 * i;
            const int row = li >> 4, c4 = li & 15;
            float4 qv = *(const float4*)&tile[row][4 * c4];
            *(float4*)(out_q + (size_t)(rb + row) * DDIM + 4 * c4) = qv;
        }
    }

#pragma unroll
    for (int off = 32; off > 0; off >>= 1) ls += __shfl_down(ls, off);
    const int lane = tid & 63;
    const int wid  = tid >> 6;
    if (lane == 0) red[wid] = ls;
    __syncthreads();
    if (tid == 0) {
        float t = (red[0] + red[1]) + (red[2] + red[3]);
        atomicAdd(out_loss, t * (1.25f / (float)(NROWS * DDIM)));  // (1+BETA)*mean
    }
}

extern "C" void kernel_launch(void* const* d_in, const int* in_sizes, int n_in,
                              void* d_out, int out_size, void* d_ws, size_t ws_size,
                              hipStream_t stream) {
    const float* x = (const float*)d_in[0];   // encoding [N, 64]
    const float* w = (const float*)d_in[1];   // weight   [512, 64]

    float* out      = (float*)d_out;
    float* out_idx  = out;
    float* out_q    = out + (size_t)NROWS;
    float* out_loss = out + (size_t)NROWS + (size_t)NROWS * DDIM;

    // half-results parked in the out_q region (4 MB of 64 MB); epilogue
    // rewrites out_q fully AFTER vq_merge's last read of mmg.
    uint2* mmg = (uint2*)out_q;

    char* ws = (char*)d_ws;
    unsigned* cnt  = (unsigned*)(ws + WS_CNT);
    float* w2p3    = (float*)(ws + WS_W2P3);
    unsigned short* whi  = (unsigned short*)(ws + WS_WHI);
    unsigned short* wmid = (unsigned short*)(ws + WS_WMID);
    unsigned* list = (unsigned*)(ws + WS_LIST);
    long cap = ((long)ws_size - WS_LIST) / 4;
    int listcap = cap > 0 ? (cap > NROWS ? NROWS : (int)cap) : 0;

    vq_prep<<<2, 256, 0, stream>>>(w, w2p3, whi, wmid, cnt, out_loss);
    vq_gemm<<<2048, 256, 0, stream>>>(x, whi, wmid, w2p3, mmg);
    vq_merge<<<NROWS / 256, 256, 0, stream>>>(mmg, out_idx, cnt, list, listcap);
    vq_recheck<<<256, 512, 0, stream>>>(x, w, cnt, list, listcap, out_idx);
    vq_epilogue<<<NROWS / 256, 256, 0, stream>>>(x, w, out_idx, out_q, out_loss);
}

// Round 7
// 248.482 us; speedup vs baseline: 1.1377x; 1.1377x over previous
//
#include <hip/hip_runtime.h>

// VectorQuantizer: N=262144 rows, D=64 dims, K=512 codewords, fp32.
// out layout (floats): [0,N) idx ; [N, N+N*D) quantized_st ; [N+N*D] vq_loss
//
// CORRECTNESS MODEL (verified R2-R5, absmax 0): reference fp32 bit pattern is
//   d2 = fl(fl(x2 - fl(2*m)) + w2), x2/w2 numpy pairwise-8 order, m = sequential
//   FMA chain d ascending (BLAS), argmin strict < (first-min tie-break).
// Two-phase: MFMA approx scores (bf16 hi/mid splits of -2w, 3 terms) +
// exact-chain recheck of rows with top-2 gap < margin. The flag/recheck logic
// is correct for ANY approx whose error <= bound.
//
// R11: REVERT setprio (R10 measured: vq_gemm 55.7->95us, MfmaUtil 38->22%,
// FETCH +27MB — T5 refuted for this structure; starves staging waves and/or
// de-syncs the even/odd block pairs sharing x rows). KEEP the R10 epilogue
// LDS-coalesced rewrite (non-gemm time dropped ~18us). vq_gemm is now
// bit-for-bit the R9 kernel that measured 55.7us / MfmaUtil 38%.
#define NROWS 262144
#define DDIM  64
#define KCB   512

// key = (fp32 bits of s''=w2+3-2*dot) << 9 | cw ; s'' in [2.8,3.2] => one
// exponent octave => bits monotone. 1 key unit = ulp(3)/512 ; MARGKEY = 3<<17
// => 768 ulps = 1.83e-4 >= 2x worst-case |approx - ref| bound (~9.1e-5).
#define MARGKEY (3u << 17)

// ws layout (bytes)
#define WS_CNT   0
#define WS_W2P3  1024
#define WS_WHI   4096
#define WS_WMID  69632
#define WS_LIST  135168

typedef __attribute__((ext_vector_type(8))) short short8;
typedef __attribute__((ext_vector_type(4))) float floatx4;
typedef __attribute__((ext_vector_type(16))) float floatx16;
typedef __attribute__((ext_vector_type(2))) unsigned int uintx2;

#if defined(__has_builtin)
#if __has_builtin(__builtin_amdgcn_permlane32_swap)
#define VQ_PLSWAP 1
#endif
#endif

__device__ __forceinline__ unsigned umin2(unsigned a, unsigned b) { return a < b ? a : b; }
__device__ __forceinline__ unsigned umax2(unsigned a, unsigned b) { return a > b ? a : b; }

// numpy FLOAT_pairwise_sum order for n=64 over terms fl(a[i]*a[i])  [R2-verified]
__device__ __forceinline__ float np_sumsq64(const float* a) {
    float r[8];
#pragma unroll
    for (int j = 0; j < 8; ++j) r[j] = __fmul_rn(a[j], a[j]);
#pragma unroll
    for (int i = 8; i < 64; i += 8) {
#pragma unroll
        for (int j = 0; j < 8; ++j)
            r[j] = __fadd_rn(r[j], __fmul_rn(a[i + j], a[i + j]));
    }
    return __fadd_rn(__fadd_rn(__fadd_rn(r[0], r[1]), __fadd_rn(r[2], r[3])),
                     __fadd_rn(__fadd_rn(r[4], r[5]), __fadd_rn(r[6], r[7])));
}

// pack two fp32 into bf16-truncate hi dword + residual-bf16 mid dword
__device__ __forceinline__ void split2(float e0, float e1, unsigned& hid, unsigned& mid) {
    unsigned u0 = __float_as_uint(e0), u1 = __float_as_uint(e1);
    float r0 = __fsub_rn(e0, __uint_as_float(u0 & 0xFFFF0000u));  // exact
    float r1 = __fsub_rn(e1, __uint_as_float(u1 & 0xFFFF0000u));  // exact
    hid = (u0 >> 16) | (u1 & 0xFFFF0000u);
    mid = (__float_as_uint(r0) >> 16) | (__float_as_uint(r1) & 0xFFFF0000u);
}

__device__ __forceinline__ void split4(float4 v, uint2& h, uint2& m) {
    unsigned h0, m0, h1, m1;
    split2(v.x, v.y, h0, m0);
    split2(v.z, v.w, h1, m1);
    h = make_uint2(h0, h1);
    m = make_uint2(m0, m1);
}

// xor-32 merge of (min1,min2) pairs across lane halves.
__device__ __forceinline__ void merge32(unsigned& m1, unsigned& m2) {
#ifdef VQ_PLSWAP
    uintx2 s1 = __builtin_amdgcn_permlane32_swap(m1, m1, false, false);
    uintx2 s2 = __builtin_amdgcn_permlane32_swap(m2, m2, false, false);
    m2 = umin2(umin2(s2[0], s2[1]), umax2(s1[0], s1[1]));
    m1 = umin2(s1[0], s1[1]);
#else
    unsigned o1 = __shfl_xor((int)m1, 32);
    unsigned o2 = __shfl_xor((int)m2, 32);
    m2 = umin2(umin2(m2, o2), umax2(m1, o1));
    m1 = umin2(m1, o1);
#endif
}

// top-2 (min1,min2) of 16 keys, balanced tree
__device__ __forceinline__ void top2_16(const unsigned* k, unsigned& m1, unsigned& m2) {
    unsigned lo[8], hi[8];
#pragma unroll
    for (int i = 0; i < 8; ++i) {
        lo[i] = umin2(k[2 * i], k[2 * i + 1]);
        hi[i] = umax2(k[2 * i], k[2 * i + 1]);
    }
#pragma unroll
    for (int s = 4; s >= 1; s >>= 1) {
#pragma unroll
        for (int i = 0; i < s; ++i) {
            unsigned l = umin2(lo[i], lo[i + s]);
            unsigned h = umin2(umax2(lo[i], lo[i + s]), umin2(hi[i], hi[i + s]));
            lo[i] = l; hi[i] = h;
        }
    }
    m1 = lo[0]; m2 = hi[0];
}

// ---- prep: w2p3 = fl(w2)+3, bf16 truncated splits of v = -2*w; zeroes
// cnt/loss (replaces memsets). Bit-identical tables to R5. ----
__global__ void vq_prep(const float* __restrict__ w, float* __restrict__ w2p3,
                        unsigned short* __restrict__ whi,
                        unsigned short* __restrict__ wmid,
                        unsigned* __restrict__ cnt, float* __restrict__ loss) {
    const int k = blockIdx.x * blockDim.x + threadIdx.x;  // 0..511
    if (k == 0) { *cnt = 0u; *loss = 0.0f; }
    float ws[64];
    const float4* wp = (const float4*)(w + (size_t)k * DDIM);
#pragma unroll
    for (int j = 0; j < 16; ++j) {
        float4 v = wp[j];
        ws[4 * j + 0] = v.x; ws[4 * j + 1] = v.y;
        ws[4 * j + 2] = v.z; ws[4 * j + 3] = v.w;
    }
    w2p3[k] = __fadd_rn(np_sumsq64(ws), 3.0f);
#pragma unroll
    for (int j = 0; j < 8; ++j) {
        union { unsigned d[4]; short8 s; } H, M;
#pragma unroll
        for (int t = 0; t < 4; ++t) {
            float v0 = __fmul_rn(-2.0f, ws[8 * j + 2 * t]);      // exact (pow2)
            float v1 = __fmul_rn(-2.0f, ws[8 * j + 2 * t + 1]);  // exact (pow2)
            split2(v0, v1, H.d[t], M.d[t]);
        }
        *(short8*)(whi  + (size_t)k * 64 + 8 * j) = H.s;
        *(short8*)(wmid + (size_t)k * 64 + 8 * j) = M.s;
    }
}

// ---- phase-1: 2048 blocks of 256 thr = 4 waves. Block = (row-tile of 256) x
// (codebook half of 256 cw). Wave owns 64 cw = 2x 32x32x16 cw-tiles; 32
// rows/iter double-buffered LDS staging. Per lane: one x-row (col=lane&31),
// 32 cw values -> lane-local top-2 -> single merge32. [R9-measured 55.7us] ----
__launch_bounds__(256, 4)
__global__ void vq_gemm(const float* __restrict__ x,
                        const unsigned short* __restrict__ whi,
                        const unsigned short* __restrict__ wmid,
                        const float* __restrict__ w2p3g,
                        uint2* __restrict__ mmg) {
    const int tid = threadIdx.x;
    const int wave = tid >> 6, lane = tid & 63;
    const int row32 = lane & 31;   // A: cw-in-tile; B: x-row; C: x-row (col)
    const int khalf = lane >> 5;   // A/B: k-subwindow; C: cw-subset offset/4
    const int half = blockIdx.x & 1;
    const int r0 = (blockIdx.x >> 1) * 256;

    __shared__ float w2p3s[256];                         // 1 KB (this half)
    __shared__ __align__(16) unsigned sbh[2][32 * 36];   // B hi tiles (9 KB)
    __shared__ __align__(16) unsigned sbm[2][32 * 36];   // B mid tiles (9 KB)
    __shared__ uint2 mm[4][8][32];                       // per-wave min1/min2 (8 KB)

    w2p3s[tid] = w2p3g[half * 256 + tid];

    // A-frags: tile tt (32 cw), k-step t (16 dims). Lane holds
    // cw = half*256 + wave*64 + tt*32 + row32, dims t*16 + khalf*8 + j.
    short8 ah[2][4], am[2][4];
#pragma unroll
    for (int tt = 0; tt < 2; ++tt) {
        const size_t cw = (size_t)(half * 256 + wave * 64 + tt * 32 + row32);
#pragma unroll
        for (int t = 0; t < 4; ++t) {
            const size_t off = cw * 64 + t * 16 + khalf * 8;
            ah[tt][t] = *(const short8*)(whi + off);
            am[tt][t] = *(const short8*)(wmid + off);
        }
    }

    // staging: 256 threads stage 32 rows x 16 float4: thread owns rows srow,
    // srow+16 at float4-col sc4.
    const int srow = tid >> 4, sc4 = tid & 15;
    {
        float4 v0 = *(const float4*)(x + (size_t)(r0 + srow) * DDIM + 4 * sc4);
        float4 v1 = *(const float4*)(x + (size_t)(r0 + srow + 16) * DDIM + 4 * sc4);
        uint2 h, m;
        split4(v0, h, m);
        *(uint2*)&sbh[0][srow * 36 + 2 * sc4] = h;
        *(uint2*)&sbm[0][srow * 36 + 2 * sc4] = m;
        split4(v1, h, m);
        *(uint2*)&sbh[0][(srow + 16) * 36 + 2 * sc4] = h;
        *(uint2*)&sbm[0][(srow + 16) * 36 + 2 * sc4] = m;
    }
    __syncthreads();

    // key cw base for this lane's C-subset: + tt*32 + (reg&3)+8*(reg>>2)
    const unsigned cwk = (unsigned)(half * 256 + wave * 64 + 4 * khalf);

    for (int it = 0; it < 8; ++it) {
        const int p = it & 1;
        float4 pre0, pre1;
        if (it < 7) {
            pre0 = *(const float4*)(x + (size_t)(r0 + (it + 1) * 32 + srow) * DDIM + 4 * sc4);
            pre1 = *(const float4*)(x + (size_t)(r0 + (it + 1) * 32 + srow + 16) * DDIM + 4 * sc4);
        }

        // B-frags: row = row32, k-step t: dwords t*8 + khalf*4 .. +3
        short8 bh[4], bm[4];
#pragma unroll
        for (int t = 0; t < 4; ++t) {
            bh[t] = *(const short8*)&sbh[p][row32 * 36 + t * 8 + khalf * 4];
            bm[t] = *(const short8*)&sbm[p][row32 * 36 + t * 8 + khalf * 4];
        }

        unsigned r1t[2], r2t[2];
#pragma unroll
        for (int tt = 0; tt < 2; ++tt) {
            // acc init: reg 4g+i -> m = i + 8g + 4*khalf (contiguous quads)
            floatx16 acc;
            const int wb = wave * 64 + tt * 32 + 4 * khalf;
#pragma unroll
            for (int g = 0; g < 4; ++g) {
                floatx4 v = *(const floatx4*)&w2p3s[wb + 8 * g];
                acc[4 * g + 0] = v[0]; acc[4 * g + 1] = v[1];
                acc[4 * g + 2] = v[2]; acc[4 * g + 3] = v[3];
            }
#pragma unroll
            for (int t = 0; t < 4; ++t) {
                acc = __builtin_amdgcn_mfma_f32_32x32x16_bf16(ah[tt][t], bh[t], acc, 0, 0, 0);
                acc = __builtin_amdgcn_mfma_f32_32x32x16_bf16(ah[tt][t], bm[t], acc, 0, 0, 0);
                acc = __builtin_amdgcn_mfma_f32_32x32x16_bf16(am[tt][t], bh[t], acc, 0, 0, 0);
            }
            // keys for this tile's 16 lane-local cw
            unsigned keys[16];
#pragma unroll
            for (int r = 0; r < 16; ++r) {
                const unsigned moff = (unsigned)((r & 3) + 8 * (r >> 2) + tt * 32);
                keys[r] = (__float_as_uint(acc[r]) << 9) + cwk + moff;
            }
            top2_16(keys, r1t[tt], r2t[tt]);
        }
        unsigned m1 = umin2(r1t[0], r1t[1]);
        unsigned m2 = umin2(umax2(r1t[0], r1t[1]), umin2(r2t[0], r2t[1]));
        merge32(m1, m2);   // combine complementary cw subsets (same x-row)
        if (lane < 32) mm[wave][it][row32] = make_uint2(m1, m2);

        if (it < 7) {
            uint2 h, m;
            split4(pre0, h, m);
            *(uint2*)&sbh[p ^ 1][srow * 36 + 2 * sc4] = h;
            *(uint2*)&sbm[p ^ 1][srow * 36 + 2 * sc4] = m;
            split4(pre1, h, m);
            *(uint2*)&sbh[p ^ 1][(srow + 16) * 36 + 2 * sc4] = h;
            *(uint2*)&sbm[p ^ 1][(srow + 16) * 36 + 2 * sc4] = m;
        }
        __syncthreads();
    }

    // deferred cross-wave merge: thread tid owns row r0+tid (it=tid>>5, rl=tid&31)
    unsigned a1 = 0xFFFFFFFFu, a2 = 0xFFFFFFFFu;
#pragma unroll
    for (int wv = 0; wv < 4; ++wv) {
        uint2 v = mm[wv][tid >> 5][tid & 31];
        a2 = umin2(umin2(a2, v.y), umax2(a1, v.x));
        a1 = umin2(a1, v.x);
    }
    mmg[(size_t)half * NROWS + (r0 + tid)] = make_uint2(a1, a2);
}

// ---- merge halves: combine the two 256-cw top-2 results per row, write idx,
// flag rows with top-2 gap < margin into the recheck list. ----
__launch_bounds__(256)
__global__ void vq_merge(const uint2* __restrict__ mmg,
                         float* __restrict__ out_idx,
                         unsigned* __restrict__ cnt,
                         unsigned* __restrict__ list, int listcap) {
    const int row = blockIdx.x * 256 + threadIdx.x;
    const int lane = threadIdx.x & 63;
    uint2 v0 = mmg[row];
    uint2 v1 = mmg[(size_t)NROWS + row];
    unsigned a1 = umin2(v0.x, v1.x);
    unsigned a2 = umin2(umax2(v0.x, v1.x), umin2(v0.y, v1.y));
    out_idx[row] = (float)(a1 & 511u);
    bool flag = (a2 - a1 < MARGKEY);
    unsigned long long mask = __ballot(flag);
    int nw = __popcll(mask);
    unsigned base = 0;
    if (lane == 0 && nw) base = atomicAdd(cnt, (unsigned)nw);
    base = (unsigned)__shfl((int)base, 0);
    if (flag) {
        unsigned pos = base + (unsigned)__popcll(mask & ((1ull << lane) - 1ull));
        if ((int)pos < listcap) list[pos] = (unsigned)row;
    }
}

// ---- recheck: R4-verified structure (thread owns codeword, exact chains,
// LDS d2 tile + exact argmin), rows indirect via flag list ----
__launch_bounds__(512, 4)
__global__ void vq_recheck(const float* __restrict__ x,
                           const float* __restrict__ w,
                           const unsigned* __restrict__ cnt,
                           const unsigned* __restrict__ list, int listcap,
                           float* __restrict__ out_idx) {
    const int tid = threadIdx.x;
    unsigned total = *cnt;
    if (total > (unsigned)listcap) total = (unsigned)listcap;
    const unsigned nb = (total + 15) >> 4;
    if (blockIdx.x >= nb) return;   // early out BEFORE the w-load (uniform)

    // this thread's codeword + its exact w2 (numpy order)
    float wl[64];
    {
        const float4* wp = (const float4*)(w + (size_t)tid * DDIM);
#pragma unroll
        for (int j = 0; j < 16; ++j) {
            float4 v = wp[j];
            wl[4 * j + 0] = v.x; wl[4 * j + 1] = v.y;
            wl[4 * j + 2] = v.z; wl[4 * j + 3] = v.w;
        }
    }
    const float w2l = np_sumsq64(wl);

    __shared__ float d2tile[16][KCB];   // 32 KB
    __shared__ int rowbuf[16];
    __shared__ float x2buf[16];

    for (unsigned batch = blockIdx.x; batch < nb; batch += gridDim.x) {
        if (tid < 16) {
            unsigned li = batch * 16 + (unsigned)tid;
            rowbuf[tid] = (li < total) ? (int)list[li] : -1;
        }
        __syncthreads();

        // x2 per row: 8 threads/row, numpy pairwise-8 order + exact shfl tree
        if (tid < 128) {
            const int rl = tid >> 3, j = tid & 7;
            int row = rowbuf[rl]; if (row < 0) row = 0;
            const float* xr = x + (size_t)row * DDIM;
            float a0 = xr[j];
            float r = __fmul_rn(a0, a0);
#pragma unroll
            for (int i = 1; i < 8; ++i) {
                float ai = xr[8 * i + j];
                r = __fadd_rn(r, __fmul_rn(ai, ai));
            }
            float s1 = __fadd_rn(r,  __shfl_xor(r, 1));
            float s2 = __fadd_rn(s1, __shfl_xor(s1, 2));
            float s4 = __fadd_rn(s2, __shfl_xor(s2, 4));
            if (j == 0) x2buf[rl] = s4;
        }
        __syncthreads();

        // exact chains: 4 rows in flight, block-uniform broadcast x loads
        for (int g = 0; g < 16; g += 4) {
            int ra = rowbuf[g + 0]; if (ra < 0) ra = 0;
            int rb = rowbuf[g + 1]; if (rb < 0) rb = 0;
            int rc = rowbuf[g + 2]; if (rc < 0) rc = 0;
            int rd = rowbuf[g + 3]; if (rd < 0) rd = 0;
            const float* xr0 = x + (size_t)ra * DDIM;
            const float* xr1 = x + (size_t)rb * DDIM;
            const float* xr2 = x + (size_t)rc * DDIM;
            const float* xr3 = x + (size_t)rd * DDIM;
            float m0 = 0.f, m1 = 0.f, m2 = 0.f, m3 = 0.f;
#pragma unroll
            for (int jb = 0; jb < 16; ++jb) {
                float4 a0 = *(const float4*)(xr0 + 4 * jb);
                float4 a1 = *(const float4*)(xr1 + 4 * jb);
                float4 a2 = *(const float4*)(xr2 + 4 * jb);
                float4 a3 = *(const float4*)(xr3 + 4 * jb);
                m0 = __fmaf_rn(a0.x, wl[4 * jb + 0], m0);
                m0 = __fmaf_rn(a0.y, wl[4 * jb + 1], m0);
                m0 = __fmaf_rn(a0.z, wl[4 * jb + 2], m0);
                m0 = __fmaf_rn(a0.w, wl[4 * jb + 3], m0);
                m1 = __fmaf_rn(a1.x, wl[4 * jb + 0], m1);
                m1 = __fmaf_rn(a1.y, wl[4 * jb + 1], m1);
                m1 = __fmaf_rn(a1.z, wl[4 * jb + 2], m1);
                m1 = __fmaf_rn(a1.w, wl[4 * jb + 3], m1);
                m2 = __fmaf_rn(a2.x, wl[4 * jb + 0], m2);
                m2 = __fmaf_rn(a2.y, wl[4 * jb + 1], m2);
                m2 = __fmaf_rn(a2.z, wl[4 * jb + 2], m2);
                m2 = __fmaf_rn(a2.w, wl[4 * jb + 3], m2);
                m3 = __fmaf_rn(a3.x, wl[4 * jb + 0], m3);
                m3 = __fmaf_rn(a3.y, wl[4 * jb + 1], m3);
                m3 = __fmaf_rn(a3.z, wl[4 * jb + 2], m3);
                m3 = __fmaf_rn(a3.w, wl[4 * jb + 3], m3);
            }
            float X0 = x2buf[g + 0], X1 = x2buf[g + 1];
            float X2 = x2buf[g + 2], X3 = x2buf[g + 3];
            d2tile[g + 0][tid] = __fadd_rn(__fsub_rn(X0, __fmul_rn(2.0f, m0)), w2l);
            d2tile[g + 1][tid] = __fadd_rn(__fsub_rn(X1, __fmul_rn(2.0f, m1)), w2l);
            d2tile[g + 2][tid] = __fadd_rn(__fsub_rn(X2, __fmul_rn(2.0f, m2)), w2l);
            d2tile[g + 3][tid] = __fadd_rn(__fsub_rn(X3, __fmul_rn(2.0f, m3)), w2l);
        }
        __syncthreads();

        // exact argmin per row: 32 threads/row, strict < first-min [R4-verified]
        {
            const int rl  = tid >> 5;
            const int sub = tid & 31;
            float bv = d2tile[rl][sub];
            int   bi = sub;
#pragma unroll
            for (int i = 1; i < 16; ++i) {
                int cc = sub + 32 * i;
                float v = d2tile[rl][cc];
                if (v < bv) { bv = v; bi = cc; }
            }
#pragma unroll
            for (int s = 1; s < 32; s <<= 1) {
                float ov = __shfl_xor(bv, s);
                int   oi = __shfl_xor(bi, s);
                if (ov < bv || (ov == bv && oi < bi)) { bv = ov; bi = oi; }
            }
            if (sub == 0 && rowbuf[rl] >= 0) out_idx[rowbuf[rl]] = (float)bi;
        }
        __syncthreads();
    }
}

// ---- epilogue: gather codeword, quantized_st = fl(x + fl(q-x)), loss.
// R10 (kept): memory path via padded LDS tiles (coalesced global load/store,
// 4x fewer transactions). Per-thread row ownership (tid->row), fmaf chain
// order, wave shfl tree, red[4] combine, atomicAdd structure UNCHANGED =>
// loss and q bit-identical to the R4-verified epilogue. ----
__launch_bounds__(256)
__global__ void vq_epilogue(const float* __restrict__ x,
                            const float* __restrict__ w,
                            const float* __restrict__ out_idx_f,
                            float* __restrict__ out_q,
                            float* __restrict__ out_loss) {
    const int tid = threadIdx.x;
    const int r0  = blockIdx.x * 256;
    const int bidx = (int)out_idx_f[r0 + tid];   // coalesced idx load
    const float4* wq = (const float4*)(w + (size_t)bidx * DDIM);

    __shared__ float tile[128][65];   // 33.3 KB, +1 pad => conflict-minimal
    __shared__ float red[4];

    float ls = 0.0f;
#pragma unroll
    for (int ph = 0; ph < 2; ++ph) {
        const int rb = r0 + ph * 128;
        __syncthreads();   // prior store-phase reads done before overwrite
        // coalesced load: 128 rows x 16 float4 = 2048 float4; 8 per thread
#pragma unroll
        for (int i = 0; i < 8; ++i) {
            const int li = tid + 256 * i;            // linear float4 index
            const int row = li >> 4, c4 = li & 15;
            float4 v = *(const float4*)(x + (size_t)(rb + row) * DDIM + 4 * c4);
            *(float4*)&tile[row][4 * c4] = v;
        }
        __syncthreads();
        // compute: threads ph*128..ph*128+127 own their row (tid->row kept)
        if ((tid >> 7) == ph) {
            const int lr = tid & 127;
#pragma unroll
            for (int j = 0; j < 16; ++j) {
                float4 xv = *(const float4*)&tile[lr][4 * j];
                float4 wv = wq[j];
                float e0 = __fsub_rn(wv.x, xv.x), e1 = __fsub_rn(wv.y, xv.y);
                float e2 = __fsub_rn(wv.z, xv.z), e3 = __fsub_rn(wv.w, xv.w);
                ls = fmaf(e0, e0, ls); ls = fmaf(e1, e1, ls);
                ls = fmaf(e2, e2, ls); ls = fmaf(e3, e3, ls);
                float4 q;
                q.x = __fadd_rn(xv.x, e0); q.y = __fadd_rn(xv.y, e1);
                q.z = __fadd_rn(xv.z, e2); q.w = __fadd_rn(xv.w, e3);
                *(float4*)&tile[lr][4 * j] = q;   // own-row slot, in place
            }
        }
        __syncthreads();
        // coalesced store of q from LDS
#pragma unroll
        for (int i = 0; i < 8; ++i) {
            const int li = tid + 256 * i;
            const int row = li >> 4, c4 = li & 15;
            float4 qv = *(const float4*)&tile[row][4 * c4];
            *(float4*)(out_q + (size_t)(rb + row) * DDIM + 4 * c4) = qv;
        }
    }

#pragma unroll
    for (int off = 32; off > 0; off >>= 1) ls += __shfl_down(ls, off);
    const int lane = tid & 63;
    const int wid  = tid >> 6;
    if (lane == 0) red[wid] = ls;
    __syncthreads();
    if (tid == 0) {
        float t = (red[0] + red[1]) + (red[2] + red[3]);
        atomicAdd(out_loss, t * (1.25f / (float)(NROWS * DDIM)));  // (1+BETA)*mean
    }
}

extern "C" void kernel_launch(void* const* d_in, const int* in_sizes, int n_in,
                              void* d_out, int out_size, void* d_ws, size_t ws_size,
                              hipStream_t stream) {
    const float* x = (const float*)d_in[0];   // encoding [N, 64]
    const float* w = (const float*)d_in[1];   // weight   [512, 64]

    float* out      = (float*)d_out;
    float* out_idx  = out;
    float* out_q    = out + (size_t)NROWS;
    float* out_loss = out + (size_t)NROWS + (size_t)NROWS * DDIM;

    // half-results parked in the out_q region (4 MB of 64 MB); epilogue
    // rewrites out_q fully AFTER vq_merge's last read of mmg.
    uint2* mmg = (uint2*)out_q;

    char* ws = (char*)d_ws;
    unsigned* cnt  = (unsigned*)(ws + WS_CNT);
    float* w2p3    = (float*)(ws + WS_W2P3);
    unsigned short* whi  = (unsigned short*)(ws + WS_WHI);
    unsigned short* wmid = (unsigned short*)(ws + WS_WMID);
    unsigned* list = (unsigned*)(ws + WS_LIST);
    long cap = ((long)ws_size - WS_LIST) / 4;
    int listcap = cap > 0 ? (cap > NROWS ? NROWS : (int)cap) : 0;

    vq_prep<<<2, 256, 0, stream>>>(w, w2p3, whi, wmid, cnt, out_loss);
    vq_gemm<<<2048, 256, 0, stream>>>(x, whi, wmid, w2p3, mmg);
    vq_merge<<<NROWS / 256, 256, 0, stream>>>(mmg, out_idx, cnt, list, listcap);
    vq_recheck<<<256, 512, 0, stream>>>(x, w, cnt, list, listcap, out_idx);
    vq_epilogue<<<NROWS / 256, 256, 0, stream>>>(x, w, out_idx, out_q, out_loss);
}